// Round 4
// baseline (429.985 us; speedup 1.0000x reference)
//
#include <hip/hip_runtime.h>

#define NN 100000
#define MM 8
#define KK 256
#define DD 64
#define BROWS 128
#define NTILES ((NN + BROWS - 1) / BROWS)   // 782

typedef _Float16 half8 __attribute__((ext_vector_type(8)));
typedef float    f32x4 __attribute__((ext_vector_type(4)));

// ---------------------------------------------------------------------------
// ws layout (bytes):
//   [0,      256K)  cb_hi  half8[MM*8*256]   chunk-major: idx = m*2048 + c*256 + k
//   [256K,   512K)  cb_lo  (scaled x2048)
//   [512K,   520K)  csq    float[MM*KK]
// ---------------------------------------------------------------------------

__global__ __launch_bounds__(256) void pq_prep_kernel(
    const float* __restrict__ cb, half8* __restrict__ whi,
    half8* __restrict__ wlo, float* __restrict__ csq)
{
    const int t = blockIdx.x * 256 + threadIdx.x;      // 0..16383
    const int m = t >> 11, rest = t & 2047;
    const int c = rest >> 8, k = rest & 255;
    const float* src = cb + ((size_t)(m * KK + k)) * DD + c * 8;
    half8 h, l;
#pragma unroll
    for (int j = 0; j < 8; ++j) {
        float v = src[j];
        _Float16 hi = (_Float16)v;
        h[j] = hi;
        l[j] = (_Float16)((v - (float)hi) * 2048.0f);
    }
    whi[t] = h;
    wlo[t] = l;

    if (t < MM * KK) {
        const float* cr = cb + (size_t)t * DD;
        float s0 = 0.f, s1 = 0.f, s2 = 0.f, s3 = 0.f;
#pragma unroll
        for (int d = 0; d < DD; d += 4) {
            s0 = fmaf(cr[d + 0], cr[d + 0], s0);
            s1 = fmaf(cr[d + 1], cr[d + 1], s1);
            s2 = fmaf(cr[d + 2], cr[d + 2], s2);
            s3 = fmaf(cr[d + 3], cr[d + 3], s3);
        }
        csq[t] = (s0 + s1) + (s2 + s3);
    }
}

// Main: block = 128 rows x 1 m x 256 k. MFMA fp16-split distances; rows whose
// top-2 MFMA distances are within DELTA get an exact fp32 rescore.
//
// R4: R3 falsified load-latency AND occupancy theories (dur invariant).
// Model (validated vs counters): per-SIMD pipe costs MFMA 91K cyc (17%
// MfmaUtil), VALU 197K cyc (41.5% VALUBusy) -> each wave serially alternates
// {wait on back-to-back dependent MFMA chain} -> {min-tracking VALU burst}.
// VGPR=84 proves compiler kept only one body's accs live (no cross-body
// overlap). Fix: explicit 2-stage pipeline with NAMED per-parity accumulators
// (pa/pb): body kt+1 MFMAs issue BEFORE body kt's tracking VALU; MFMAs
// interleaved across the 4 independent accumulators (per-acc accumulation
// order identical to R1 -> bit-identical arithmetic). No arrays, no runtime
// indices (R2 scratch lesson).
#define DELTA 4.0e-3f

#define MFMA16(A, B, C) __builtin_amdgcn_mfma_f32_16x16x32_f16(A, B, C, 0, 0, 0)

// issue prefetch of k-tile KT into named B-set S (4 independent 16B loads)
#define PF(S, KT)                                                          \
    {                                                                      \
        const int o_ = (KT) * 16 + ci;                                     \
        S##h0 = bh0p[o_]; S##h1 = bh1p[o_];                                \
        S##l0 = bl0p[o_]; S##l1 = bl1p[o_];                                \
    }

// 12 MFMAs for one body into named acc set P, reading B-set S.
// Interleaved across the 4 independent accumulators; per-accumulator
// order identical to R1's sequential form (bit-identical results).
#define MFMA_BODY(P, S)                                                    \
    {                                                                      \
        P##1_0 = MFMA16(Ah[0][0], S##h0, z);                               \
        P##1_1 = MFMA16(Ah[1][0], S##h0, z);                               \
        P##2_0 = MFMA16(Ah[0][0], S##l0, z);                               \
        P##2_1 = MFMA16(Ah[1][0], S##l0, z);                               \
        P##1_0 = MFMA16(Ah[0][1], S##h1, P##1_0);                          \
        P##1_1 = MFMA16(Ah[1][1], S##h1, P##1_1);                          \
        P##2_0 = MFMA16(Ah[0][1], S##l1, P##2_0);                          \
        P##2_1 = MFMA16(Ah[1][1], S##l1, P##2_1);                          \
        P##2_0 = MFMA16(Al[0][0], S##h0, P##2_0);                          \
        P##2_1 = MFMA16(Al[1][0], S##h0, P##2_1);                          \
        P##2_0 = MFMA16(Al[0][1], S##h1, P##2_0);                          \
        P##2_1 = MFMA16(Al[1][1], S##h1, P##2_1);                          \
    }

// dist + min/second-min tracking for body KT, reading named acc set P.
// R1-identical arithmetic: cross = acc1 + acc2*(1/2048); d = cq - 2*cross.
#define TRACK_BODY(P, KT)                                                  \
    {                                                                      \
        const int k_ = (KT) * 16 + ci;                                     \
        const float cq_ = csq_s[k_];                                       \
        _Pragma("unroll")                                                  \
        for (int r = 0; r < 4; ++r) {                                      \
            float cross0 = P##1_0[r] + P##2_0[r] * (1.0f / 2048.0f);       \
            float d0 = cq_ - 2.0f * cross0;                                \
            if (d0 < d1v[0][r]) {                                          \
                d2v[0][r] = d1v[0][r];                                     \
                d1v[0][r] = d0; k1v[0][r] = k_;                            \
            } else if (d0 < d2v[0][r]) {                                   \
                d2v[0][r] = d0;                                            \
            }                                                              \
            float cross1 = P##1_1[r] + P##2_1[r] * (1.0f / 2048.0f);       \
            float d1 = cq_ - 2.0f * cross1;                                \
            if (d1 < d1v[1][r]) {                                          \
                d2v[1][r] = d1v[1][r];                                     \
                d1v[1][r] = d1; k1v[1][r] = k_;                            \
            } else if (d1 < d2v[1][r]) {                                   \
                d2v[1][r] = d1;                                            \
            }                                                              \
        }                                                                  \
    }

__global__ __launch_bounds__(256, 3) void pq_main_kernel(
    const float* __restrict__ x, const half8* __restrict__ whi,
    const half8* __restrict__ wlo, const float* __restrict__ csqg,
    const float* __restrict__ cbf, float* __restrict__ qout,
    float* __restrict__ idout)
{
    __shared__ float csq_s[KK];     // 1 KB
    __shared__ int   cand_k[BROWS]; // 512 B

    const int m   = blockIdx.y;
    const int n0  = blockIdx.x * BROWS;
    const int tid = threadIdx.x;
    const int w = tid >> 6, L = tid & 63;
    const int q = L >> 4, ci = L & 15;

    csq_s[tid] = csqg[m * KK + tid];

    // A fragments: d = t*32 + q*8 + j on BOTH operands -> k-slot permutation
    // cancels (same mapping on A and B).
    half8 Ah[2][2], Al[2][2];
#pragma unroll
    for (int rb = 0; rb < 2; ++rb) {
        int n = n0 + w * 32 + rb * 16 + ci;
        if (n > NN - 1) n = NN - 1;                    // tail clamp (writes guarded)
        const float4* xp = (const float4*)(x + (size_t)n * (MM * DD) + m * DD);
#pragma unroll
        for (int t = 0; t < 2; ++t) {
            float4 v0 = xp[t * 8 + q * 2 + 0];
            float4 v1 = xp[t * 8 + q * 2 + 1];
            float vs[8] = {v0.x, v0.y, v0.z, v0.w, v1.x, v1.y, v1.z, v1.w};
#pragma unroll
            for (int j = 0; j < 8; ++j) {
                _Float16 hi = (_Float16)vs[j];
                Ah[rb][t][j] = hi;
                Al[rb][t][j] = (_Float16)((vs[j] - (float)hi) * 2048.0f);
            }
        }
    }

    // per-lane best (d1,k1) and second-best value d2, per output row slot
    float d1v[2][4], d2v[2][4];
    int   k1v[2][4];
#pragma unroll
    for (int rb = 0; rb < 2; ++rb)
#pragma unroll
        for (int r = 0; r < 4; ++r) { d1v[rb][r] = 3.4e38f; d2v[rb][r] = 3.4e38f; k1v[rb][r] = 0; }

    // Per-lane B fragment pointers: c-chunk = q (low 32 dims) and 4+q (high).
    const half8* bh0p = whi + m * 2048 + q * 256;
    const half8* bh1p = whi + m * 2048 + (4 + q) * 256;
    const half8* bl0p = wlo + m * 2048 + q * 256;
    const half8* bl1p = wlo + m * 2048 + (4 + q) * 256;

    __syncthreads();                                   // csq_s ready

    const f32x4 z = {0.f, 0.f, 0.f, 0.f};

    // named B-sets (E/O) and per-parity acc sets (pa = even bodies, pb = odd)
    half8 Eh0, Eh1, El0, El1;
    half8 Oh0, Oh1, Ol0, Ol1;
    f32x4 pa1_0, pa1_1, pa2_0, pa2_1;
    f32x4 pb1_0, pb1_1, pb2_0, pb2_1;

    // 2-stage pipeline: MFMA(body kt+1) issues before TRACK(body kt), so each
    // wave's tracking VALU hides its own MFMA chain latency.
    PF(E, 0)
    PF(O, 1)
    MFMA_BODY(pa, E)                      // body 0
    PF(E, 2)   MFMA_BODY(pb, O)  TRACK_BODY(pa, 0)
    PF(O, 3)   MFMA_BODY(pa, E)  TRACK_BODY(pb, 1)
    PF(E, 4)   MFMA_BODY(pb, O)  TRACK_BODY(pa, 2)
    PF(O, 5)   MFMA_BODY(pa, E)  TRACK_BODY(pb, 3)
    PF(E, 6)   MFMA_BODY(pb, O)  TRACK_BODY(pa, 4)
    PF(O, 7)   MFMA_BODY(pa, E)  TRACK_BODY(pb, 5)
    PF(E, 8)   MFMA_BODY(pb, O)  TRACK_BODY(pa, 6)
    PF(O, 9)   MFMA_BODY(pa, E)  TRACK_BODY(pb, 7)
    PF(E, 10)  MFMA_BODY(pb, O)  TRACK_BODY(pa, 8)
    PF(O, 11)  MFMA_BODY(pa, E)  TRACK_BODY(pb, 9)
    PF(E, 12)  MFMA_BODY(pb, O)  TRACK_BODY(pa, 10)
    PF(O, 13)  MFMA_BODY(pa, E)  TRACK_BODY(pb, 11)
    PF(E, 14)  MFMA_BODY(pb, O)  TRACK_BODY(pa, 12)
    PF(O, 15)  MFMA_BODY(pa, E)  TRACK_BODY(pb, 13)
               MFMA_BODY(pb, O)  TRACK_BODY(pa, 14)
                                 TRACK_BODY(pb, 15)

    // Finalize each of the 8 row-slots: butterfly argmin; near-ties -> exact
    // fp32 rescore (R1 arithmetic, empirically bit-matching numpy's argmin).
#pragma unroll
    for (int rb = 0; rb < 2; ++rb)
#pragma unroll
        for (int r = 0; r < 4; ++r) {
            float d = d1v[rb][r];
            int   k = k1v[rb][r];
            for (int mask = 1; mask < 16; mask <<= 1) {
                float ds = __shfl_xor(d, mask);
                int   ks = __shfl_xor(k, mask);
                if (ds < d || (ds == d && ks < k)) { d = ds; k = ks; }
            }
            const float thr = d + DELTA;               // d == dmin, uniform
            int cnt = (d1v[rb][r] <= thr ? 1 : 0) + (d2v[rb][r] <= thr ? 1 : 0);
            for (int mask = 1; mask < 16; mask <<= 1) cnt += __shfl_xor(cnt, mask);

            const int n = n0 + w * 32 + rb * 16 + q * 4 + r;
            if (cnt > 1 && n < NN) {                   // rare exact path (q-group uniform)
                const float* xr = x + (size_t)n * (MM * DD) + m * DD;
                float s0 = 0.f, s1 = 0.f, s2 = 0.f, s3 = 0.f;
                for (int dd = 0; dd < DD; dd += 4) {
                    s0 = fmaf(xr[dd + 0], xr[dd + 0], s0);
                    s1 = fmaf(xr[dd + 1], xr[dd + 1], s1);
                    s2 = fmaf(xr[dd + 2], xr[dd + 2], s2);
                    s3 = fmaf(xr[dd + 3], xr[dd + 3], s3);
                }
                const float xsq = (s0 + s1) + (s2 + s3);
                float bd = 3.4e38f; int bk = 0;
                for (int j = 0; j < 16; ++j) {         // lane ci: k = ci + 16j (ascending)
                    const int kk = ci + 16 * j;
                    const float* c0 = cbf + ((size_t)(m * KK + kk)) * DD;
                    float a0 = 0.f, a1 = 0.f;
                    for (int dd = 0; dd < DD; dd += 2) {
                        a0 = fmaf(c0[dd + 0], xr[dd + 0], a0);
                        a1 = fmaf(c0[dd + 1], xr[dd + 1], a1);
                    }
                    const float dist = (xsq - 2.f * (a0 + a1)) + csq_s[kk];
                    if (dist < bd) { bd = dist; bk = kk; }   // strict <, ascending k
                }
                for (int mask = 1; mask < 16; mask <<= 1) {
                    float db = __shfl_xor(bd, mask);
                    int   kb = __shfl_xor(bk, mask);
                    if (db < bd || (db == bd && kb < bk)) { bd = db; bk = kb; }
                }
                k = bk;
            }
            if (ci == r) cand_k[w * 32 + rb * 16 + q * 4 + r] = k;
        }
    __syncthreads();

    if (tid < BROWS) {
        int n = n0 + tid;
        if (n < NN) idout[(size_t)m * NN + n] = (float)cand_k[tid];
    }
    for (int i = 0; i < 8; ++i) {
        int row = i * 16 + (tid >> 4);
        int n = n0 + row;
        if (n < NN) {
            int k = cand_k[row];
            int j = tid & 15;
            float4 v = ((const float4*)cbf)[(m * KK + k) * 16 + j];
            ((float4*)(qout + (size_t)n * (MM * DD) + m * DD))[j] = v;
        }
    }
}

extern "C" void kernel_launch(void* const* d_in, const int* in_sizes, int n_in,
                              void* d_out, int out_size, void* d_ws, size_t ws_size,
                              hipStream_t stream)
{
    const float* x  = (const float*)d_in[0];
    const float* cb = (const float*)d_in[1];

    float* qout  = (float*)d_out;
    float* idout = qout + (size_t)NN * (MM * DD);

    half8* whi = (half8*)d_ws;
    half8* wlo = (half8*)((char*)d_ws + 256 * 1024);
    float* csq = (float*)((char*)d_ws + 512 * 1024);

    pq_prep_kernel<<<dim3(64), dim3(256), 0, stream>>>(cb, whi, wlo, csq);

    pq_main_kernel<<<dim3(NTILES, MM), dim3(256), 0, stream>>>(
        x, whi, wlo, csq, cb, qout, idout);
}